// Round 1
// baseline (381.277 us; speedup 1.0000x reference)
//
#include <hip/hip_runtime.h>
#include <hip/hip_bf16.h>
#include <cstdint>

#define D_IN  4096
#define D_OUT 4096

typedef __attribute__((ext_vector_type(8))) __bf16 bf16x8;
typedef __attribute__((ext_vector_type(4))) float  f32x4;

typedef const __attribute__((address_space(1))) unsigned g_u32;
typedef __attribute__((address_space(3))) unsigned       l_u32;

__device__ __forceinline__ unsigned short f32_to_bf16_bits(float f) {
    union { float f; unsigned u; } v; v.f = f;
    unsigned r = v.u + 0x7fffu + ((v.u >> 16) & 1u);   // RNE
    return (unsigned short)(r >> 16);
}

// ---------------- pass 1: quantize x (scalar maxabs) and convert to bf16 ----
__global__ void quant_x_kernel(const float* __restrict__ x,
                               unsigned short* __restrict__ xq,
                               const float* __restrict__ xscale, int n) {
    int i = (blockIdx.x * blockDim.x + threadIdx.x) * 4;
    if (i >= n) return;
    float s    = fmaxf(xscale[0], 1e-8f);
    float step = s * (1.0f / 127.0f);
    float inv  = 127.0f / s;
    float4 v = *(const float4*)(x + i);
    ushort4 o;
    o.x = f32_to_bf16_bits(fminf(fmaxf(rintf(v.x * inv), -127.f), 127.f) * step);
    o.y = f32_to_bf16_bits(fminf(fmaxf(rintf(v.y * inv), -127.f), 127.f) * step);
    o.z = f32_to_bf16_bits(fminf(fmaxf(rintf(v.z * inv), -127.f), 127.f) * step);
    o.w = f32_to_bf16_bits(fminf(fmaxf(rintf(v.w * inv), -127.f), 127.f) * step);
    *(ushort4*)(xq + i) = o;
}

// ---------------- pass 2: convert W (K x N) to bf16, transposed -> Wt (N x K)
__global__ void convW_kernel(const float* __restrict__ W,
                             unsigned short* __restrict__ Wt) {
    __shared__ float tile[32][33];
    int n0 = blockIdx.x * 32, k0 = blockIdx.y * 32;
    tile[threadIdx.y][threadIdx.x] =
        W[(size_t)(k0 + threadIdx.y) * D_OUT + n0 + threadIdx.x];
    __syncthreads();
    Wt[(size_t)(n0 + threadIdx.y) * D_IN + k0 + threadIdx.x] =
        f32_to_bf16_bits(tile[threadIdx.x][threadIdx.y]);
}

// ---------------- pass 3: bf16 GEMM (m97 structure) + bias epilogue ---------
// A : [M][K] bf16 (quantized x), Bt : [N][K] bf16 (W transposed), C : [M][N] f32
__global__ void gemm_kernel(const unsigned short* __restrict__ A,
                            const unsigned short* __restrict__ Bt,
                            const float* __restrict__ bias,
                            float* __restrict__ C, int M) {
    constexpr int BM = 128, BN = 128, BK = 64, K = D_IN, N = D_OUT;
    __shared__ unsigned short lds_a[BM * BK];   // [128][64] row-major, linear
    __shared__ unsigned short lds_b[BN * BK];

    const int tid  = threadIdx.x;
    const int lane = tid & 63;
    const int wid  = tid >> 6;

    const int nTn = N / BN;                     // 32
    const int nwg = gridDim.x;                  // 2048, %8 == 0
    int bid = blockIdx.x;
    int swz = (bid & 7) * (nwg >> 3) + (bid >> 3);   // XCD-aware, bijective
    const int tm = swz / nTn, tn = swz % nTn;
    const int row0 = tm * BM, col0 = tn * BN;
    const int wr = wid >> 1, wc = wid & 1;      // 2x2 wave grid, 64x64 each

    f32x4 acc[4][4];
#pragma unroll
    for (int m = 0; m < 4; ++m)
#pragma unroll
        for (int n = 0; n < 4; ++n) acc[m][n] = (f32x4){0.f, 0.f, 0.f, 0.f};

    const unsigned short* Abase = A  + (size_t)row0 * K;
    const unsigned short* Bbase = Bt + (size_t)col0 * K;

    for (int kt = 0; kt < K; kt += BK) {
        // ---- stage A,B tiles: 16 KiB each via global_load_lds width 16 ----
#pragma unroll
        for (int i = 0; i < 4; ++i) {
            int e = (i * 256 + tid) * 8;        // linear bf16 elem index
            int r = e >> 6, c = e & 63;
            __builtin_amdgcn_global_load_lds(
                (g_u32*)(Abase + (size_t)r * K + kt + c),
                (l_u32*)(&lds_a[e]), 16, 0, 0);
        }
#pragma unroll
        for (int i = 0; i < 4; ++i) {
            int e = (i * 256 + tid) * 8;
            int r = e >> 6, c = e & 63;
            __builtin_amdgcn_global_load_lds(
                (g_u32*)(Bbase + (size_t)r * K + kt + c),
                (l_u32*)(&lds_b[e]), 16, 0, 0);
        }
        __syncthreads();

        // ---- compute: 2 K-halves x 4x4 fragments ----
#pragma unroll
        for (int h = 0; h < 2; ++h) {
            bf16x8 af[4], bfr[4];
#pragma unroll
            for (int m = 0; m < 4; ++m) {
                int row = wr * 64 + m * 16 + (lane & 15);
                af[m] = *(const bf16x8*)&lds_a[row * BK + h * 32 + (lane >> 4) * 8];
            }
#pragma unroll
            for (int n = 0; n < 4; ++n) {
                int row = wc * 64 + n * 16 + (lane & 15);
                bfr[n] = *(const bf16x8*)&lds_b[row * BK + h * 32 + (lane >> 4) * 8];
            }
#pragma unroll
            for (int m = 0; m < 4; ++m)
#pragma unroll
                for (int n = 0; n < 4; ++n)
                    acc[m][n] = __builtin_amdgcn_mfma_f32_16x16x32_bf16(
                        af[m], bfr[n], acc[m][n], 0, 0, 0);
        }
        __syncthreads();
    }

    // ---- epilogue: C = acc + bias ----
    const int lr = (lane >> 4) * 4, lc = lane & 15;
#pragma unroll
    for (int n = 0; n < 4; ++n) {
        int col = col0 + wc * 64 + n * 16 + lc;
        float bv = bias[col];
#pragma unroll
        for (int m = 0; m < 4; ++m) {
            int rowb = row0 + wr * 64 + m * 16 + lr;
            f32x4 v = acc[m][n];
#pragma unroll
            for (int r = 0; r < 4; ++r)
                C[(size_t)(rowb + r) * N + col] = v[r] + bv;
        }
    }
}

extern "C" void kernel_launch(void* const* d_in, const int* in_sizes, int n_in,
                              void* d_out, int out_size, void* d_ws, size_t ws_size,
                              hipStream_t stream) {
    const float* x      = (const float*)d_in[0];   // [4,2048,4096] f32
    const float* W      = (const float*)d_in[1];   // [4096,4096] f32
    const float* xscale = (const float*)d_in[2];   // scalar
    const float* bias   = (const float*)d_in[3];   // [4096] f32
    float* out = (float*)d_out;

    const int nx = in_sizes[0];            // 33554432
    const int M  = nx / D_IN;              // 8192

    unsigned short* xq = (unsigned short*)d_ws;                         // 64 MiB
    unsigned short* Wt = (unsigned short*)((char*)d_ws + (size_t)nx * 2); // 32 MiB

    quant_x_kernel<<<nx / 4 / 256, 256, 0, stream>>>(x, xq, xscale, nx);

    dim3 tb(32, 32);
    dim3 tg(D_OUT / 32, D_IN / 32);
    convW_kernel<<<tg, tb, 0, stream>>>(W, Wt);

    int grid = (M / 128) * (D_OUT / 128);  // 2048
    gemm_kernel<<<grid, 256, 0, stream>>>(xq, Wt, bias, out, M);
}

// Round 2
// 303.009 us; speedup vs baseline: 1.2583x; 1.2583x over previous
//
#include <hip/hip_runtime.h>
#include <hip/hip_bf16.h>
#include <cstdint>

#define D_IN  4096
#define D_OUT 4096

typedef __attribute__((ext_vector_type(8))) __bf16 bf16x8;
typedef __attribute__((ext_vector_type(4))) float  f32x4;

typedef const __attribute__((address_space(1))) unsigned g_u32;
typedef __attribute__((address_space(3))) unsigned       l_u32;

__device__ __forceinline__ unsigned short f32_to_bf16_bits(float f) {
    union { float f; unsigned u; } v; v.f = f;
    unsigned r = v.u + 0x7fffu + ((v.u >> 16) & 1u);   // RNE
    return (unsigned short)(r >> 16);
}

// ---------------- pass 1: quantize x (scalar maxabs) and convert to bf16 ----
__global__ void quant_x_kernel(const float* __restrict__ x,
                               unsigned short* __restrict__ xq,
                               const float* __restrict__ xscale, int n) {
    int i = (blockIdx.x * blockDim.x + threadIdx.x) * 4;
    if (i >= n) return;
    float s    = fmaxf(xscale[0], 1e-8f);
    float step = s * (1.0f / 127.0f);
    float inv  = 127.0f / s;
    float4 v = *(const float4*)(x + i);
    ushort4 o;
    o.x = f32_to_bf16_bits(fminf(fmaxf(rintf(v.x * inv), -127.f), 127.f) * step);
    o.y = f32_to_bf16_bits(fminf(fmaxf(rintf(v.y * inv), -127.f), 127.f) * step);
    o.z = f32_to_bf16_bits(fminf(fmaxf(rintf(v.z * inv), -127.f), 127.f) * step);
    o.w = f32_to_bf16_bits(fminf(fmaxf(rintf(v.w * inv), -127.f), 127.f) * step);
    *(ushort4*)(xq + i) = o;
}

// ---------------- pass 2: convert W (K x N) to bf16, transposed -> Wt (N x K)
__global__ void convW_kernel(const float* __restrict__ W,
                             unsigned short* __restrict__ Wt) {
    __shared__ float tile[32][33];
    int n0 = blockIdx.x * 32, k0 = blockIdx.y * 32;
    tile[threadIdx.y][threadIdx.x] =
        W[(size_t)(k0 + threadIdx.y) * D_OUT + n0 + threadIdx.x];
    __syncthreads();
    Wt[(size_t)(n0 + threadIdx.y) * D_IN + k0 + threadIdx.x] =
        f32_to_bf16_bits(tile[threadIdx.x][threadIdx.y]);
}

// ---------------- pass 3: 256x256 8-phase bf16 GEMM + bias epilogue --------
// A : [M][K] bf16, Bt : [N][K] bf16, C : [M][N] f32
// Schedule per K-tile t (4 phases; 8 phases per 2-tile loop body):
//  p1: ds_read A[m0-3],B[n0-1] (12) | stage B1(t+1)->nxt | bar | lgkm0 | 16 MFMA | bar
//  p2: ds_read B[n2-3] (4)         |                    | bar | lgkm0 | 16 MFMA | bar
//  p3: ds_read A[m4-7] (8)         | stage B0(t+2)->cur | bar | lgkm0 | 16 MFMA | bar
//  p4:                             | stage A (t+2)->cur | vmcnt(6) | bar | 16 MFMA | bar
// Steady-state: 3 half-tiles (6 loads) in flight across the K-tile boundary.
// Safety: each region's overwrite is issued >=1 barrier-pair after its last read
// (A reads end p3 -> staged p4; B0 reads end p2 -> staged p3; B1 -> staged p1').
__global__ __launch_bounds__(512, 2)
void gemm_kernel(const unsigned short* __restrict__ A,
                 const unsigned short* __restrict__ Bt,
                 const float* __restrict__ bias,
                 float* __restrict__ C, int M) {
    constexpr int K = D_IN, N = D_OUT, BK = 64;
    constexpr int NT = K / BK;                 // 64 K-tiles
    __shared__ unsigned short lds[2 * 32768];  // 2 x (A 32KiB + B 32KiB) = 128 KiB

    const int tid  = threadIdx.x;
    const int lane = tid & 63;
    const int wid  = tid >> 6;
    const int wr   = wid >> 2;                 // 0..1  (M)
    const int wc   = wid & 3;                  // 0..3  (N)

    // bijective XCD-aware block swizzle
    const int nTn = N / 256;
    const int nwg = gridDim.x;
    int bid = blockIdx.x;
    int q8 = nwg >> 3, r8 = nwg & 7;
    int xcd = bid & 7, idx = bid >> 3;
    int swz = (xcd < r8 ? xcd * (q8 + 1) : r8 * (q8 + 1) + (xcd - r8) * q8) + idx;
    const int tm = swz / nTn, tn = swz % nTn;
    const int row0 = tm * 256, col0 = tn * 256;

    // staging chunk offsets. LDS dest stays LINEAR (chunk p = (i*512+tid)*16);
    // the XOR swizzle sw = p ^ ((p>>7)&7)<<4 is applied to the global SOURCE,
    // so physical LDS chunk p holds logical bytes sw(p) (involution).
    int srcOff[4], dstOff[4];
#pragma unroll
    for (int i = 0; i < 4; ++i) {
        int p  = (i * 512 + tid) * 16;
        int sw = p ^ (((p >> 7) & 7) << 4);
        dstOff[i] = p;
        srcOff[i] = (sw >> 7) * (K * 2) + (sw & 127);
    }

    const char* srcA = (const char*)(A  + (size_t)row0 * K);
    const char* srcB = (const char*)(Bt + (size_t)col0 * K);
    char* ldsb = (char*)lds;

    auto STAGE4 = [&](const char* src, char* dst) {
#pragma unroll
        for (int i = 0; i < 4; ++i)
            __builtin_amdgcn_global_load_lds((g_u32*)(src + srcOff[i]),
                                             (l_u32*)(dst + dstOff[i]), 16, 0, 0);
    };
    auto STAGE2 = [&](const char* src, char* dst) {
#pragma unroll
        for (int i = 0; i < 2; ++i)
            __builtin_amdgcn_global_load_lds((g_u32*)(src + srcOff[i]),
                                             (l_u32*)(dst + dstOff[i]), 16, 0, 0);
    };

    // ---- prologue: tile0 full (8 loads) + tile1 {B0, A} (6 loads) ----
    STAGE4(srcA, ldsb);                                   // A(0)  -> buf0
    STAGE2(srcB, ldsb + 32768);                           // B0(0) -> buf0
    STAGE2(srcB + 128 * K * 2, ldsb + 32768 + 16384);     // B1(0) -> buf0
    STAGE2(srcB + 128,           ldsb + 65536 + 32768);   // B0(1) -> buf1
    STAGE4(srcA + 128,           ldsb + 65536);           // A(1)  -> buf1

    f32x4 acc[8][4];
#pragma unroll
    for (int m = 0; m < 8; ++m)
#pragma unroll
        for (int n = 0; n < 4; ++n) acc[m][n] = (f32x4){0.f, 0.f, 0.f, 0.f};

    // swizzled per-lane read bases (row&7 == lane&7 for all our frag rows)
    const int cp0 = (((lane >> 4) << 4)) ^ ((lane & 7) << 4);
    const int cp1 = cp0 ^ 64;
    const int aBase = (wr * 128 + (lane & 15)) * 128;     // bytes in A region
    const int bBase = (wc * 64  + (lane & 15)) * 128;     // bytes in B region

    asm volatile("s_waitcnt vmcnt(6)" ::: "memory");      // tile0 resident
    __builtin_amdgcn_s_barrier();

    auto KITER = [&](int t, char* cur, char* nxt) {
        bf16x8 a[4][2], b01[2][2], b23[2][2];
        const char* cA = cur;
        const char* cB = cur + 32768;

        // ---------------- phase 1: quadrant (m0-3, n0-1) ----------------
#pragma unroll
        for (int m = 0; m < 4; ++m) {
            a[m][0] = *(const bf16x8*)(cA + aBase + m * 2048 + cp0);
            a[m][1] = *(const bf16x8*)(cA + aBase + m * 2048 + cp1);
        }
#pragma unroll
        for (int n = 0; n < 2; ++n) {
            b01[n][0] = *(const bf16x8*)(cB + bBase + n * 2048 + cp0);
            b01[n][1] = *(const bf16x8*)(cB + bBase + n * 2048 + cp1);
        }
        if (t + 1 < NT) STAGE2(srcB + 128 * K * 2 + (t + 1) * 128, nxt + 32768 + 16384);
        __builtin_amdgcn_s_barrier();
        asm volatile("s_waitcnt lgkmcnt(0)" ::: "memory");
        __builtin_amdgcn_s_setprio(1);
#pragma unroll
        for (int m = 0; m < 4; ++m)
#pragma unroll
            for (int n = 0; n < 2; ++n) {
                acc[m][n] = __builtin_amdgcn_mfma_f32_16x16x32_bf16(a[m][0], b01[n][0], acc[m][n], 0, 0, 0);
                acc[m][n] = __builtin_amdgcn_mfma_f32_16x16x32_bf16(a[m][1], b01[n][1], acc[m][n], 0, 0, 0);
            }
        __builtin_amdgcn_s_setprio(0);
        __builtin_amdgcn_s_barrier();

        // ---------------- phase 2: quadrant (m0-3, n2-3) ----------------
#pragma unroll
        for (int n = 0; n < 2; ++n) {
            b23[n][0] = *(const bf16x8*)(cB + bBase + 4096 + n * 2048 + cp0);
            b23[n][1] = *(const bf16x8*)(cB + bBase + 4096 + n * 2048 + cp1);
        }
        __builtin_amdgcn_s_barrier();
        asm volatile("s_waitcnt lgkmcnt(0)" ::: "memory");
        __builtin_amdgcn_s_setprio(1);
#pragma unroll
        for (int m = 0; m < 4; ++m)
#pragma unroll
            for (int n = 0; n < 2; ++n) {
                acc[m][n + 2] = __builtin_amdgcn_mfma_f32_16x16x32_bf16(a[m][0], b23[n][0], acc[m][n + 2], 0, 0, 0);
                acc[m][n + 2] = __builtin_amdgcn_mfma_f32_16x16x32_bf16(a[m][1], b23[n][1], acc[m][n + 2], 0, 0, 0);
            }
        __builtin_amdgcn_s_setprio(0);
        __builtin_amdgcn_s_barrier();

        // ---------------- phase 3: quadrant (m4-7, n2-3) ----------------
#pragma unroll
        for (int m = 0; m < 4; ++m) {
            a[m][0] = *(const bf16x8*)(cA + aBase + 8192 + m * 2048 + cp0);
            a[m][1] = *(const bf16x8*)(cA + aBase + 8192 + m * 2048 + cp1);
        }
        if (t + 2 < NT) STAGE2(srcB + (t + 2) * 128, cur + 32768);
        __builtin_amdgcn_s_barrier();
        asm volatile("s_waitcnt lgkmcnt(0)" ::: "memory");
        __builtin_amdgcn_s_setprio(1);
#pragma unroll
        for (int m = 0; m < 4; ++m)
#pragma unroll
            for (int n = 0; n < 2; ++n) {
                acc[m + 4][n + 2] = __builtin_amdgcn_mfma_f32_16x16x32_bf16(a[m][0], b23[n][0], acc[m + 4][n + 2], 0, 0, 0);
                acc[m + 4][n + 2] = __builtin_amdgcn_mfma_f32_16x16x32_bf16(a[m][1], b23[n][1], acc[m + 4][n + 2], 0, 0, 0);
            }
        __builtin_amdgcn_s_setprio(0);
        __builtin_amdgcn_s_barrier();

        // ---------------- phase 4: quadrant (m4-7, n0-1) ----------------
        if (t + 2 < NT) {
            STAGE4(srcA + (t + 2) * 128, cur);
            asm volatile("s_waitcnt vmcnt(6)" ::: "memory");   // tile t+1 resident
        } else {
            asm volatile("s_waitcnt vmcnt(0)" ::: "memory");
        }
        __builtin_amdgcn_s_barrier();
        __builtin_amdgcn_s_setprio(1);
#pragma unroll
        for (int m = 0; m < 4; ++m)
#pragma unroll
            for (int n = 0; n < 2; ++n) {
                acc[m + 4][n] = __builtin_amdgcn_mfma_f32_16x16x32_bf16(a[m][0], b01[n][0], acc[m + 4][n], 0, 0, 0);
                acc[m + 4][n] = __builtin_amdgcn_mfma_f32_16x16x32_bf16(a[m][1], b01[n][1], acc[m + 4][n], 0, 0, 0);
            }
        __builtin_amdgcn_s_setprio(0);
        __builtin_amdgcn_s_barrier();
    };

    for (int t = 0; t < NT; t += 2) {
        KITER(t,     ldsb,         ldsb + 65536);
        KITER(t + 1, ldsb + 65536, ldsb);
    }

    // ---- epilogue: C = acc + bias ----
    const int lr = (lane >> 4) * 4, lc = lane & 15;
#pragma unroll
    for (int n = 0; n < 4; ++n) {
        int col = col0 + wc * 64 + n * 16 + lc;
        float bv = bias[col];
#pragma unroll
        for (int m = 0; m < 8; ++m) {
            int rowb = row0 + wr * 128 + m * 16 + lr;
            f32x4 v = acc[m][n];
#pragma unroll
            for (int r2 = 0; r2 < 4; ++r2)
                C[(size_t)(rowb + r2) * N + col] = v[r2] + bv;
        }
    }
}

extern "C" void kernel_launch(void* const* d_in, const int* in_sizes, int n_in,
                              void* d_out, int out_size, void* d_ws, size_t ws_size,
                              hipStream_t stream) {
    const float* x      = (const float*)d_in[0];   // [4,2048,4096] f32
    const float* W      = (const float*)d_in[1];   // [4096,4096] f32
    const float* xscale = (const float*)d_in[2];   // scalar
    const float* bias   = (const float*)d_in[3];   // [4096] f32
    float* out = (float*)d_out;

    const int nx = in_sizes[0];            // 33554432
    const int M  = nx / D_IN;              // 8192

    unsigned short* xq = (unsigned short*)d_ws;                           // 64 MiB
    unsigned short* Wt = (unsigned short*)((char*)d_ws + (size_t)nx * 2); // 32 MiB

    quant_x_kernel<<<nx / 4 / 256, 256, 0, stream>>>(x, xq, xscale, nx);

    dim3 tb(32, 32);
    dim3 tg(D_OUT / 32, D_IN / 32);
    convW_kernel<<<tg, tb, 0, stream>>>(W, Wt);

    int grid = (M / 256) * (D_OUT / 256);  // 512
    gemm_kernel<<<grid, 512, 0, stream>>>(xq, Wt, bias, out, M);
}